// Round 3
// baseline (14008.919 us; speedup 1.0000x reference)
//
#include <hip/hip_runtime.h>
#include <hip/hip_bf16.h>
#include <math.h>

// ---------------------------------------------------------------------------
// GraphEncoder: lin0 -> LSTM0 -> 3x(GATv2 -> LN+ELU -> LSTM) -> meanpool ->
//               MLP head with LayerNorms.
// fp32 compute; xl/xr stored bf16 to shrink workspace.
// Workspace (~401 MiB):
//   hbuf f32 [N*H] | cbuf f32 [N*H] | ybuf f32 [N*H] |
//   xl bf16 [N*H]  | xr bf16 [N*H]  | elog f32 [EP*4] | nmax/nsum f32 [N*4]
// Aliases: gbuf (f32, CHK*1024) overlays xr; pooled/cnt/z1 overlay xl.
// (Round 3 = resubmission of round 2; that bench died on container infra,
//  not on the kernel.)
// ---------------------------------------------------------------------------

constexpr int NN    = 100000;
constexpr int EE    = 400000;
constexpr int EP    = EE + NN;      // +self loops = 500000
constexpr int BG    = 4096;
constexpr int FIN   = 300;
constexpr int HEADS = 4;
constexpr int HID   = 256;          // H = HEADS*64
constexpr int G4H   = 1024;         // 4*H
constexpr int NH1   = 512;
constexpr int NH2   = 768;
constexpr int CHK   = 12500;        // LSTM row chunk (8 chunks); CHK*G4H*4 = 51.2MB

__device__ inline float sigm(float x) { return 1.f / (1.f + expf(-x)); }

__device__ inline void atomicMaxF(float* addr, float val) {
    if (val >= 0.f) atomicMax((int*)addr, __float_as_int(val));
    else            atomicMin((unsigned int*)addr, __float_as_uint(val));
}

// ---------------- zero fill -------------------------------------------------
__global__ __launch_bounds__(256) void zero_f32(float* __restrict__ p, long long n)
{
    long long i = (long long)blockIdx.x * 256 + threadIdx.x;
    long long stride = (long long)gridDim.x * 256;
    for (; i < n; i += stride) p[i] = 0.f;
}

// ---------------- GEMM: C[M x Nw] = A[M x K] @ W[Nw x K]^T (+bias +bias2) ----
#define BM 64
#define BN 64
#define BKT 16

__global__ __launch_bounds__(256) void gemm_bias_f32(
    const float* __restrict__ A, const float* __restrict__ W,
    const float* __restrict__ bias, const float* __restrict__ bias2,
    float* __restrict__ C, int M, int K, int Nw, int accum)
{
    __shared__ float As[BKT][BM + 1];
    __shared__ float Ws[BKT][BN + 1];
    const int tid = threadIdx.x;
    const int tx = tid & 15, ty = tid >> 4;
    const int row0 = blockIdx.x * BM;
    const int col0 = blockIdx.y * BN;
    float acc[4][4] = {};

    for (int k0 = 0; k0 < K; k0 += BKT) {
#pragma unroll
        for (int i = 0; i < 4; ++i) {
            int li = tid + i * 256;       // 0..1023
            int r  = li >> 4;
            int kk = li & 15;
            int gk = k0 + kk;
            int gr = row0 + r;
            As[kk][r] = (gr < M && gk < K) ? A[(size_t)gr * K + gk] : 0.f;
            int gc = col0 + r;            // always < Nw (Nw % 64 == 0)
            Ws[kk][r] = (gk < K) ? W[(size_t)gc * K + gk] : 0.f;
        }
        __syncthreads();
#pragma unroll
        for (int kk = 0; kk < BKT; ++kk) {
            float a[4], b[4];
#pragma unroll
            for (int i = 0; i < 4; ++i) a[i] = As[kk][ty * 4 + i];
#pragma unroll
            for (int j = 0; j < 4; ++j) b[j] = Ws[kk][tx * 4 + j];
#pragma unroll
            for (int i = 0; i < 4; ++i)
#pragma unroll
                for (int j = 0; j < 4; ++j)
                    acc[i][j] += a[i] * b[j];
        }
        __syncthreads();
    }
#pragma unroll
    for (int i = 0; i < 4; ++i) {
        int gr = row0 + ty * 4 + i;
        if (gr >= M) continue;
#pragma unroll
        for (int j = 0; j < 4; ++j) {
            int gc = col0 + tx * 4 + j;
            float v = acc[i][j];
            if (bias)  v += bias[gc];
            if (bias2) v += bias2[gc];
            size_t idx = (size_t)gr * Nw + gc;
            if (accum) v += C[idx];
            C[idx] = v;
        }
    }
}

__global__ __launch_bounds__(256) void gemm_bias_bf16(
    const float* __restrict__ A, const float* __restrict__ W,
    const float* __restrict__ bias,
    __hip_bfloat16* __restrict__ C, int M, int K, int Nw)
{
    __shared__ float As[BKT][BM + 1];
    __shared__ float Ws[BKT][BN + 1];
    const int tid = threadIdx.x;
    const int tx = tid & 15, ty = tid >> 4;
    const int row0 = blockIdx.x * BM;
    const int col0 = blockIdx.y * BN;
    float acc[4][4] = {};

    for (int k0 = 0; k0 < K; k0 += BKT) {
#pragma unroll
        for (int i = 0; i < 4; ++i) {
            int li = tid + i * 256;
            int r  = li >> 4;
            int kk = li & 15;
            int gk = k0 + kk;
            int gr = row0 + r;
            As[kk][r] = (gr < M && gk < K) ? A[(size_t)gr * K + gk] : 0.f;
            int gc = col0 + r;
            Ws[kk][r] = (gk < K) ? W[(size_t)gc * K + gk] : 0.f;
        }
        __syncthreads();
#pragma unroll
        for (int kk = 0; kk < BKT; ++kk) {
            float a[4], b[4];
#pragma unroll
            for (int i = 0; i < 4; ++i) a[i] = As[kk][ty * 4 + i];
#pragma unroll
            for (int j = 0; j < 4; ++j) b[j] = Ws[kk][tx * 4 + j];
#pragma unroll
            for (int i = 0; i < 4; ++i)
#pragma unroll
                for (int j = 0; j < 4; ++j)
                    acc[i][j] += a[i] * b[j];
        }
        __syncthreads();
    }
#pragma unroll
    for (int i = 0; i < 4; ++i) {
        int gr = row0 + ty * 4 + i;
        if (gr >= M) continue;
#pragma unroll
        for (int j = 0; j < 4; ++j) {
            int gc = col0 + tx * 4 + j;
            float v = acc[i][j];
            if (bias) v += bias[gc];
            C[(size_t)gr * Nw + gc] = __float2bfloat16(v);
        }
    }
}

// ---------------- GATv2 edge kernels ----------------------------------------
__global__ __launch_bounds__(256) void init_gat(float* __restrict__ nmax,
                                                float* __restrict__ nsum)
{
    int idx = blockIdx.x * 256 + threadIdx.x;
    if (idx >= NN * HEADS) return;
    nmax[idx] = -INFINITY;
    nsum[idx] = 0.f;
}

// one 64-lane wave per edge; lane l handles channel l of every head
__global__ __launch_bounds__(256) void edge_logits(
    const __hip_bfloat16* __restrict__ xl, const __hip_bfloat16* __restrict__ xr,
    const int* __restrict__ ei, const float* __restrict__ att,
    float* __restrict__ elog, float* __restrict__ nmax)
{
    int wid  = blockIdx.x * 4 + (threadIdx.x >> 6);
    int lane = threadIdx.x & 63;
    if (wid >= EP) return;
    int s, d;
    if (wid < EE) { s = ei[wid]; d = ei[EE + wid]; }
    else          { s = d = wid - EE; }
    float p[HEADS];
#pragma unroll
    for (int h = 0; h < HEADS; ++h) {
        float v = __bfloat162float(xl[(size_t)s * HID + h * 64 + lane]) +
                  __bfloat162float(xr[(size_t)d * HID + h * 64 + lane]);
        v = (v >= 0.f) ? v : 0.2f * v;          // leaky_relu(., 0.2)
        p[h] = v * att[h * 64 + lane];
    }
#pragma unroll
    for (int off = 32; off > 0; off >>= 1)
#pragma unroll
        for (int h = 0; h < HEADS; ++h) p[h] += __shfl_down(p[h], off);
    if (lane == 0) {
#pragma unroll
        for (int h = 0; h < HEADS; ++h) {
            elog[(size_t)wid * HEADS + h] = p[h];
            atomicMaxF(&nmax[d * HEADS + h], p[h]);
        }
    }
}

__global__ __launch_bounds__(256) void edge_alpha(
    float* __restrict__ elog, const float* __restrict__ nmax,
    float* __restrict__ nsum, const int* __restrict__ ei)
{
    int idx = blockIdx.x * 256 + threadIdx.x;
    if (idx >= EP * HEADS) return;
    int e = idx >> 2, h = idx & 3;
    int d = (e < EE) ? ei[EE + e] : e - EE;
    float a = expf(elog[idx] - nmax[d * HEADS + h]);
    elog[idx] = a;
    atomicAdd(&nsum[d * HEADS + h], a);
}

__global__ __launch_bounds__(256) void edge_scatter(
    const float* __restrict__ alpha, const float* __restrict__ nsum,
    const __hip_bfloat16* __restrict__ xl, const int* __restrict__ ei,
    float* __restrict__ y)
{
    int wid  = blockIdx.x * 4 + (threadIdx.x >> 6);
    int lane = threadIdx.x & 63;
    if (wid >= EP) return;
    int s, d;
    if (wid < EE) { s = ei[wid]; d = ei[EE + wid]; }
    else          { s = d = wid - EE; }
    float w[HEADS];
#pragma unroll
    for (int h = 0; h < HEADS; ++h)
        w[h] = alpha[(size_t)wid * HEADS + h] / nsum[d * HEADS + h];
#pragma unroll
    for (int h = 0; h < HEADS; ++h)
        atomicAdd(&y[(size_t)d * HID + h * 64 + lane],
                  w[h] * __bfloat162float(xl[(size_t)s * HID + h * 64 + lane]));
}

// ---------------- LayerNorm (+optional in-bias, +activation) ----------------
// one 256-thread block per row; width in {256, 512, 768}; act: 0 none, 1 relu, 2 elu
__global__ __launch_bounds__(256) void ln_act_kernel(
    const float* __restrict__ in, const float* __restrict__ inbias,
    const float* __restrict__ gamma, const float* __restrict__ beta,
    float* __restrict__ out, int width, int act)
{
    int row = blockIdx.x;
    const float* ip = in + (size_t)row * width;
    float vals[3];
    float s = 0.f, ss = 0.f;
    int nw = width >> 8;
    for (int i = 0; i < nw; ++i) {
        int c = threadIdx.x + (i << 8);
        float v = ip[c];
        if (inbias) v += inbias[c];
        vals[i] = v; s += v; ss += v * v;
    }
#pragma unroll
    for (int off = 32; off > 0; off >>= 1) {
        s  += __shfl_down(s, off);
        ss += __shfl_down(ss, off);
    }
    __shared__ float sh[8];
    int wv = threadIdx.x >> 6, lane = threadIdx.x & 63;
    if (lane == 0) { sh[wv] = s; sh[4 + wv] = ss; }
    __syncthreads();
    if (threadIdx.x == 0) {
        sh[0] = sh[0] + sh[1] + sh[2] + sh[3];
        sh[4] = sh[4] + sh[5] + sh[6] + sh[7];
    }
    __syncthreads();
    float mean = sh[0] / width;
    float var  = sh[4] / width - mean * mean;
    float inv  = rsqrtf(var + 1e-5f);
    for (int i = 0; i < nw; ++i) {
        int c = threadIdx.x + (i << 8);
        float v = (vals[i] - mean) * inv * gamma[c] + beta[c];
        if (act == 1)      v = fmaxf(v, 0.f);
        else if (act == 2) v = (v > 0.f) ? v : expm1f(v);
        out[(size_t)row * width + c] = v;
    }
}

// ---------------- LSTM pointwise update -------------------------------------
__global__ __launch_bounds__(256) void lstm_update(
    const float* __restrict__ gates, float* __restrict__ h,
    float* __restrict__ c, int rows, int r0)
{
    int idx = blockIdx.x * 256 + threadIdx.x;
    if (idx >= rows * HID) return;
    int r = idx / HID, j = idx - r * HID;
    const float* g = gates + (size_t)r * G4H;
    float gi = g[j], gf = g[HID + j], gg = g[2 * HID + j], go = g[3 * HID + j];
    size_t gidx = (size_t)(r0 + r) * HID + j;
    float c2 = sigm(gf) * c[gidx] + sigm(gi) * tanhf(gg);
    float h2 = sigm(go) * tanhf(c2);
    c[gidx] = c2;
    h[gidx] = h2;
}

// ---------------- pooling ---------------------------------------------------
__global__ __launch_bounds__(256) void pool_sum(
    const float* __restrict__ h, const int* __restrict__ batch,
    float* __restrict__ pooled, float* __restrict__ cnt)
{
    int wid  = blockIdx.x * 4 + (threadIdx.x >> 6);
    int lane = threadIdx.x & 63;
    if (wid >= NN) return;
    int b = batch[wid];
    if (lane == 0) atomicAdd(&cnt[b], 1.f);
#pragma unroll
    for (int i = 0; i < 4; ++i)
        atomicAdd(&pooled[(size_t)b * HID + i * 64 + lane],
                  h[(size_t)wid * HID + i * 64 + lane]);
}

__global__ __launch_bounds__(256) void pool_div(float* __restrict__ pooled,
                                                const float* __restrict__ cnt)
{
    int idx = blockIdx.x * 256 + threadIdx.x;
    if (idx >= BG * HID) return;
    pooled[idx] /= fmaxf(cnt[idx / HID], 1.f);
}

// ---------------------------------------------------------------------------
extern "C" void kernel_launch(void* const* d_in, const int* in_sizes, int n_in,
                              void* d_out, int out_size, void* d_ws, size_t ws_size,
                              hipStream_t stream)
{
    (void)in_sizes; (void)n_in; (void)out_size; (void)ws_size;
    const float* x      = (const float*)d_in[0];
    const int*   ei     = (const int*)d_in[1];
    const int*   batch  = (const int*)d_in[2];
    const float* lin0_w = (const float*)d_in[4];
    const float* lin0_b = (const float*)d_in[5];
    const float* r0_wih = (const float*)d_in[6];
    // d_in[7] = rnn0_whh unused: h == 0 at first step
    const float* r0_bih = (const float*)d_in[8];
    const float* r0_bhh = (const float*)d_in[9];
    const float* mh1_w  = (const float*)d_in[46];
    const float* mh1_b  = (const float*)d_in[47];
    const float* ln1_g  = (const float*)d_in[48];
    const float* ln1_b  = (const float*)d_in[49];
    const float* mh2_w  = (const float*)d_in[50];
    const float* mh2_b  = (const float*)d_in[51];
    const float* ln2_g  = (const float*)d_in[52];
    const float* ln2_b  = (const float*)d_in[53];
    float* out = (float*)d_out;

    // ---- workspace layout (401 MiB) ----
    const size_t NH = (size_t)NN * HID;        // 25,600,000
    float* hbuf = (float*)d_ws;
    float* cbuf = hbuf + NH;
    float* ybuf = cbuf + NH;
    __hip_bfloat16* xl = (__hip_bfloat16*)(ybuf + NH);
    __hip_bfloat16* xr = xl + NH;
    float* elog = (float*)(xr + NH);
    float* nmax = elog + (size_t)EP * HEADS;
    float* nsum = nmax + (size_t)NN * HEADS;
    // aliases (dead ranges)
    float* gbuf   = (float*)xr;                // CHK*G4H*4 = 51.2MB == xr bytes
    float* pooled = (float*)xl;                // BG*HID
    float* cnt    = pooled + (size_t)BG * HID; // BG
    float* z1     = cnt + BG;                  // BG*NH1

    auto zero = [&](float* p, long long n) {
        zero_f32<<<dim3(2048), dim3(256), 0, stream>>>(p, n);
    };
    auto gemm = [&](const float* A, const float* W, const float* b1, const float* b2,
                    float* Cm, int M, int K, int Nw, int accum) {
        dim3 g((M + BM - 1) / BM, Nw / BN);
        gemm_bias_f32<<<g, dim3(256), 0, stream>>>(A, W, b1, b2, Cm, M, K, Nw, accum);
    };
    auto gemmb = [&](const float* A, const float* W, const float* b1,
                     __hip_bfloat16* Cm, int M, int K, int Nw) {
        dim3 g((M + BM - 1) / BM, Nw / BN);
        gemm_bias_bf16<<<g, dim3(256), 0, stream>>>(A, W, b1, Cm, M, K, Nw);
    };

    zero(hbuf, 2LL * NH);   // h and c contiguous

    // x0 = lin0(x) -> ybuf ; rnn0 step from zero state (h=0 -> skip whh gemm)
    gemm(x, lin0_w, lin0_b, nullptr, ybuf, NN, FIN, HID, 0);
    for (int r0 = 0; r0 < NN; r0 += CHK) {
        gemm(ybuf + (size_t)r0 * HID, r0_wih, r0_bih, r0_bhh, gbuf, CHK, HID, G4H, 0);
        lstm_update<<<dim3((CHK * HID + 255) / 256), dim3(256), 0, stream>>>(
            gbuf, hbuf, cbuf, CHK, r0);
    }

    for (int l = 0; l < 3; ++l) {
        int base = 10 + 12 * l;
        const float* wl  = (const float*)d_in[base + 0];
        const float* bl  = (const float*)d_in[base + 1];
        const float* wr  = (const float*)d_in[base + 2];
        const float* br  = (const float*)d_in[base + 3];
        const float* att = (const float*)d_in[base + 4];
        const float* gb  = (const float*)d_in[base + 5];
        const float* lg  = (const float*)d_in[base + 6];
        const float* lb  = (const float*)d_in[base + 7];
        const float* wih = (const float*)d_in[base + 8];
        const float* whh = (const float*)d_in[base + 9];
        const float* bih = (const float*)d_in[base + 10];
        const float* bhh = (const float*)d_in[base + 11];
        const float* xi = (l == 0) ? x : hbuf;
        int K = (l == 0) ? FIN : HID;

        gemmb(xi, wl, bl, xl, NN, K, HID);
        gemmb(xi, wr, br, xr, NN, K, HID);
        init_gat<<<dim3((NN * HEADS + 255) / 256), dim3(256), 0, stream>>>(nmax, nsum);
        zero(ybuf, NH);
        edge_logits<<<dim3((EP + 3) / 4), dim3(256), 0, stream>>>(xl, xr, ei, att, elog, nmax);
        edge_alpha<<<dim3((EP * HEADS + 255) / 256), dim3(256), 0, stream>>>(elog, nmax, nsum, ei);
        edge_scatter<<<dim3((EP + 3) / 4), dim3(256), 0, stream>>>(elog, nsum, xl, ei, ybuf);
        ln_act_kernel<<<dim3(NN), dim3(256), 0, stream>>>(ybuf, gb, lg, lb, ybuf, HID, 2);
        // LSTM step (gbuf overlays xr: xr dead after edge_logits)
        for (int r0 = 0; r0 < NN; r0 += CHK) {
            gemm(ybuf + (size_t)r0 * HID, wih, bih, bhh, gbuf, CHK, HID, G4H, 0);
            gemm(hbuf + (size_t)r0 * HID, whh, nullptr, nullptr, gbuf, CHK, HID, G4H, 1);
            lstm_update<<<dim3((CHK * HID + 255) / 256), dim3(256), 0, stream>>>(
                gbuf, hbuf, cbuf, CHK, r0);
        }
    }

    // mean pool over batch, then MLP head (pooled/cnt/z1 overlay dead xl)
    zero(pooled, (long long)BG * HID + BG);
    pool_sum<<<dim3((NN + 3) / 4), dim3(256), 0, stream>>>(hbuf, batch, pooled, cnt);
    pool_div<<<dim3((BG * HID + 255) / 256), dim3(256), 0, stream>>>(pooled, cnt);

    gemm(pooled, mh1_w, mh1_b, nullptr, z1, BG, HID, NH1, 0);
    ln_act_kernel<<<dim3(BG), dim3(256), 0, stream>>>(z1, nullptr, ln1_g, ln1_b, z1, NH1, 1);
    gemm(z1, mh2_w, mh2_b, nullptr, out, BG, NH1, NH2, 0);
    ln_act_kernel<<<dim3(BG), dim3(256), 0, stream>>>(out, nullptr, ln2_g, ln2_b, out, NH2, 0);
}

// Round 4
// 4570.872 us; speedup vs baseline: 3.0648x; 3.0648x over previous
//
#include <hip/hip_runtime.h>
#include <hip/hip_bf16.h>
#include <math.h>

// ---------------------------------------------------------------------------
// GraphEncoder round 4: all GEMMs -> bf16 MFMA (16x16x32), m97-style 128x128
// tile, BK=32, global_load_lds(16B) staging with XOR slot swizzle.
// fp32 kept for: LSTM c state, GAT y accumulation, all LayerNorms, gates.
// M padded to MP=100096 (782*128); K=300 padded to 320 (zeros both operands).
// Workspace (~427 MB):
//   cb f32[MP*256] | yb f32[MP*256] (xb bf16[MP*320] aliases yb; xb dead
//   before first zero(yb)) | hbb,ybb,xl,xr bf16[MP*256] | elog,nmax,nsum |
//   wpack bf16 (~5.7MB). gbuf f32[6400*1024] aliases xr (dead in LSTM phase);
//   pooled/cnt/z1/z1b/poolb alias xl (dead after last edge_scatter).
// ---------------------------------------------------------------------------

constexpr int NN    = 100000;
constexpr int EE    = 400000;
constexpr int EP    = EE + NN;      // 500000
constexpr int BG    = 4096;
constexpr int FIN   = 300;
constexpr int HEADS = 4;
constexpr int HID   = 256;
constexpr int G4H   = 1024;
constexpr int NH1   = 512;
constexpr int NH2   = 768;
constexpr int MP    = 100096;       // 782*128
constexpr int KP0   = 320;          // FIN padded to mult of 32
constexpr int CHKP  = 6400;         // LSTM chunk rows (50*128)

typedef __attribute__((ext_vector_type(4))) float f32x4;
typedef __attribute__((ext_vector_type(8))) short s16x8;

__device__ inline float sigm(float x) { return 1.f / (1.f + expf(-x)); }
__device__ inline float b2f(short s) { return __uint_as_float(((unsigned)(unsigned short)s) << 16); }
__device__ inline short f2b(float f) {
    unsigned u = __float_as_uint(f);
    u += 0x7fff + ((u >> 16) & 1);          // round-to-nearest-even
    return (short)(u >> 16);
}

__device__ inline void atomicMaxF(float* addr, float val) {
    if (val >= 0.f) atomicMax((int*)addr, __float_as_int(val));
    else            atomicMin((unsigned int*)addr, __float_as_uint(val));
}

// ---------------- utility kernels -------------------------------------------
__global__ __launch_bounds__(256) void zero_f32(float* __restrict__ p, long long n)
{
    long long i = (long long)blockIdx.x * 256 + threadIdx.x;
    long long stride = (long long)gridDim.x * 256;
    for (; i < n; i += stride) p[i] = 0.f;
}

// f32 -> bf16 with optional row/col padding (pad = 0)
__global__ __launch_bounds__(256) void conv_bf16(
    const float* __restrict__ src, short* __restrict__ dst,
    int rsrc, int rdst, int Ks, int Kd)
{
    long long n = (long long)rdst * Kd;
    long long stride = (long long)gridDim.x * 256;
    for (long long i = (long long)blockIdx.x * 256 + threadIdx.x; i < n; i += stride) {
        int r = (int)(i / Kd);
        int k = (int)(i - (long long)r * Kd);
        float v = (r < rsrc && k < Ks) ? src[(long long)r * Ks + k] : 0.f;
        dst[i] = f2b(v);
    }
}

// ---------------- MFMA GEMM -------------------------------------------------
// C[M x N] = A1[M x K1] @ B1[N x K1]^T  (+ A2[M x K2] @ B2[N x K2]^T)
// A,B bf16 (as short), K-contiguous rows. M,N multiples of 128; K mult of 32.
// Epilogue: + bias1[n] + bias2[n]; writes f32 (Cf) or bf16 (Cb).
__global__ __launch_bounds__(256) void mfma_gemm(
    const short* __restrict__ A1, const short* __restrict__ B1, int K1,
    const short* __restrict__ A2, const short* __restrict__ B2, int K2,
    const float* __restrict__ bias1, const float* __restrict__ bias2,
    float* __restrict__ Cf, short* __restrict__ Cb, int N)
{
    __shared__ __align__(16) short sA[128 * 32];
    __shared__ __align__(16) short sB[128 * 32];
    const int tid  = threadIdx.x;
    const int w    = tid >> 6, lane = tid & 63;
    const int wr   = w >> 1,  wc   = w & 1;      // 2x2 waves of 64x64
    const int row0 = blockIdx.x * 128, col0 = blockIdx.y * 128;

    f32x4 acc[4][4];
#pragma unroll
    for (int m = 0; m < 4; ++m)
#pragma unroll
        for (int n = 0; n < 4; ++n) acc[m][n] = (f32x4){0.f, 0.f, 0.f, 0.f};

    const int rs = lane >> 2;      // staging: row within 16-row segment
    const int cs = lane & 3;       // staging: LDS 16B-slot within row
    const int KK = K1 + K2;

    for (int k0 = 0; k0 < KK; k0 += 32) {
        const short* Ak; const short* Bk; int kk, ld;
        if (k0 < K1) { Ak = A1; Bk = B1; kk = k0;      ld = K1; }
        else         { Ak = A2; Bk = B2; kk = k0 - K1; ld = K2; }
#pragma unroll
        for (int i = 0; i < 2; ++i) {
            int seg = w * 2 + i;
            int row = seg * 16 + rs;                    // 0..127
            int c8  = cs ^ ((row + (row >> 2)) & 3);    // inverse-swizzled source slot
            const short* ga = Ak + (size_t)(row0 + row) * ld + kk + c8 * 8;
            const short* gb = Bk + (size_t)(col0 + row) * ld + kk + c8 * 8;
            short* la = sA + seg * 512 + lane * 8;      // linear dest: base + lane*16B
            short* lb = sB + seg * 512 + lane * 8;
            __builtin_amdgcn_global_load_lds((const __attribute__((address_space(1))) void*)ga,
                                             (__attribute__((address_space(3))) void*)la, 16, 0, 0);
            __builtin_amdgcn_global_load_lds((const __attribute__((address_space(1))) void*)gb,
                                             (__attribute__((address_space(3))) void*)lb, 16, 0, 0);
        }
        __syncthreads();   // drains vmcnt+lgkmcnt

        s16x8 af[4], bg[4];
        {
            const int rl = lane & 15;
            const int cw = lane >> 4;                   // k-chunk 0..3
#pragma unroll
            for (int m = 0; m < 4; ++m) {
                int r  = wr * 64 + m * 16 + rl;
                int sl = cw ^ ((r + (r >> 2)) & 3);     // swizzled read slot
                af[m] = *(const s16x8*)(sA + r * 32 + sl * 8);
                int c  = wc * 64 + m * 16 + rl;
                int sc = cw ^ ((c + (c >> 2)) & 3);
                bg[m] = *(const s16x8*)(sB + c * 32 + sc * 8);
            }
        }
#pragma unroll
        for (int m = 0; m < 4; ++m)
#pragma unroll
            for (int n = 0; n < 4; ++n)
                acc[m][n] = __builtin_amdgcn_mfma_f32_16x16x32_bf16(af[m], bg[n], acc[m][n], 0, 0, 0);
        __syncthreads();
    }

    // epilogue: C/D layout col=lane&15, row=(lane>>4)*4+reg  [m89-verified]
    const int cbase = col0 + wc * 64 + (lane & 15);
    const int rbase = row0 + wr * 64 + (lane >> 4) * 4;
#pragma unroll
    for (int n = 0; n < 4; ++n) {
        int col = cbase + n * 16;
        float badd = (bias1 ? bias1[col] : 0.f) + (bias2 ? bias2[col] : 0.f);
#pragma unroll
        for (int m = 0; m < 4; ++m) {
#pragma unroll
            for (int r = 0; r < 4; ++r) {
                int row = rbase + m * 16 + r;
                float v = acc[m][n][r] + badd;
                size_t idx = (size_t)row * N + col;
                if (Cb) Cb[idx] = f2b(v);
                else    Cf[idx] = v;
            }
        }
    }
}

// ---------------- GATv2 edge kernels ----------------------------------------
__global__ __launch_bounds__(256) void init_gat(float* __restrict__ nmax,
                                                float* __restrict__ nsum)
{
    int idx = blockIdx.x * 256 + threadIdx.x;
    if (idx >= NN * HEADS) return;
    nmax[idx] = -INFINITY;
    nsum[idx] = 0.f;
}

__global__ __launch_bounds__(256) void edge_logits(
    const short* __restrict__ xl, const short* __restrict__ xr,
    const int* __restrict__ ei, const float* __restrict__ att,
    float* __restrict__ elog, float* __restrict__ nmax)
{
    int wid  = blockIdx.x * 4 + (threadIdx.x >> 6);
    int lane = threadIdx.x & 63;
    if (wid >= EP) return;
    int s, d;
    if (wid < EE) { s = ei[wid]; d = ei[EE + wid]; }
    else          { s = d = wid - EE; }
    float p[HEADS];
#pragma unroll
    for (int h = 0; h < HEADS; ++h) {
        float v = b2f(xl[(size_t)s * HID + h * 64 + lane]) +
                  b2f(xr[(size_t)d * HID + h * 64 + lane]);
        v = (v >= 0.f) ? v : 0.2f * v;
        p[h] = v * att[h * 64 + lane];
    }
#pragma unroll
    for (int off = 32; off > 0; off >>= 1)
#pragma unroll
        for (int h = 0; h < HEADS; ++h) p[h] += __shfl_down(p[h], off);
    if (lane == 0) {
#pragma unroll
        for (int h = 0; h < HEADS; ++h) {
            elog[(size_t)wid * HEADS + h] = p[h];
            atomicMaxF(&nmax[d * HEADS + h], p[h]);
        }
    }
}

__global__ __launch_bounds__(256) void edge_alpha(
    float* __restrict__ elog, const float* __restrict__ nmax,
    float* __restrict__ nsum, const int* __restrict__ ei)
{
    int idx = blockIdx.x * 256 + threadIdx.x;
    if (idx >= EP * HEADS) return;
    int e = idx >> 2, h = idx & 3;
    int d = (e < EE) ? ei[EE + e] : e - EE;
    float a = expf(elog[idx] - nmax[d * HEADS + h]);
    elog[idx] = a;
    atomicAdd(&nsum[d * HEADS + h], a);
}

__global__ __launch_bounds__(256) void edge_scatter(
    const float* __restrict__ alpha, const float* __restrict__ nsum,
    const short* __restrict__ xl, const int* __restrict__ ei,
    float* __restrict__ y)
{
    int wid  = blockIdx.x * 4 + (threadIdx.x >> 6);
    int lane = threadIdx.x & 63;
    if (wid >= EP) return;
    int s, d;
    if (wid < EE) { s = ei[wid]; d = ei[EE + wid]; }
    else          { s = d = wid - EE; }
    float wgt[HEADS];
#pragma unroll
    for (int h = 0; h < HEADS; ++h)
        wgt[h] = alpha[(size_t)wid * HEADS + h] / nsum[d * HEADS + h];
#pragma unroll
    for (int h = 0; h < HEADS; ++h)
        atomicAdd(&y[(size_t)d * HID + h * 64 + lane],
                  wgt[h] * b2f(xl[(size_t)s * HID + h * 64 + lane]));
}

// ---------------- LayerNorm (+in-bias, +act), f32 in, f32 or bf16 out -------
__global__ __launch_bounds__(256) void ln_act_kernel(
    const float* __restrict__ in, const float* __restrict__ inbias,
    const float* __restrict__ gamma, const float* __restrict__ beta,
    float* __restrict__ outf, short* __restrict__ outb, int width, int act)
{
    int row = blockIdx.x;
    const float* ip = in + (size_t)row * width;
    float vals[3];
    float s = 0.f, ss = 0.f;
    int nw = width >> 8;
    for (int i = 0; i < nw; ++i) {
        int c = threadIdx.x + (i << 8);
        float v = ip[c];
        if (inbias) v += inbias[c];
        vals[i] = v; s += v; ss += v * v;
    }
#pragma unroll
    for (int off = 32; off > 0; off >>= 1) {
        s  += __shfl_down(s, off);
        ss += __shfl_down(ss, off);
    }
    __shared__ float sh[8];
    int wv = threadIdx.x >> 6, lane = threadIdx.x & 63;
    if (lane == 0) { sh[wv] = s; sh[4 + wv] = ss; }
    __syncthreads();
    if (threadIdx.x == 0) {
        sh[0] = sh[0] + sh[1] + sh[2] + sh[3];
        sh[4] = sh[4] + sh[5] + sh[6] + sh[7];
    }
    __syncthreads();
    float mean = sh[0] / width;
    float var  = sh[4] / width - mean * mean;
    float inv  = rsqrtf(var + 1e-5f);
    for (int i = 0; i < nw; ++i) {
        int c = threadIdx.x + (i << 8);
        float v = (vals[i] - mean) * inv * gamma[c] + beta[c];
        if (act == 1)      v = fmaxf(v, 0.f);
        else if (act == 2) v = (v > 0.f) ? v : expm1f(v);
        if (outb) outb[(size_t)row * width + c] = f2b(v);
        else      outf[(size_t)row * width + c] = v;
    }
}

// ---------------- LSTM pointwise update -------------------------------------
__global__ __launch_bounds__(256) void lstm_update(
    const float* __restrict__ gates, short* __restrict__ hb,
    float* __restrict__ c, int rows, int r0)
{
    int idx = blockIdx.x * 256 + threadIdx.x;
    if (idx >= rows * HID) return;
    int r = idx / HID, j = idx - r * HID;
    const float* g = gates + (size_t)r * G4H;
    float gi = g[j], gf = g[HID + j], gg = g[2 * HID + j], go = g[3 * HID + j];
    size_t gidx = (size_t)(r0 + r) * HID + j;
    float c2 = sigm(gf) * c[gidx] + sigm(gi) * tanhf(gg);
    float h2 = sigm(go) * tanhf(c2);
    c[gidx] = c2;
    hb[gidx] = f2b(h2);
}

// ---------------- pooling ---------------------------------------------------
__global__ __launch_bounds__(256) void pool_sum(
    const short* __restrict__ h, const int* __restrict__ batch,
    float* __restrict__ pooled, float* __restrict__ cnt)
{
    int wid  = blockIdx.x * 4 + (threadIdx.x >> 6);
    int lane = threadIdx.x & 63;
    if (wid >= NN) return;
    int b = batch[wid];
    if (lane == 0) atomicAdd(&cnt[b], 1.f);
#pragma unroll
    for (int i = 0; i < 4; ++i)
        atomicAdd(&pooled[(size_t)b * HID + i * 64 + lane],
                  b2f(h[(size_t)wid * HID + i * 64 + lane]));
}

__global__ __launch_bounds__(256) void pool_div(
    const float* __restrict__ pooled, const float* __restrict__ cnt,
    short* __restrict__ poolb)
{
    int idx = blockIdx.x * 256 + threadIdx.x;
    if (idx >= BG * HID) return;
    poolb[idx] = f2b(pooled[idx] / fmaxf(cnt[idx / HID], 1.f));
}

// ---------------------------------------------------------------------------
extern "C" void kernel_launch(void* const* d_in, const int* in_sizes, int n_in,
                              void* d_out, int out_size, void* d_ws, size_t ws_size,
                              hipStream_t stream)
{
    (void)in_sizes; (void)n_in; (void)out_size; (void)ws_size;
    const float* x      = (const float*)d_in[0];
    const int*   ei     = (const int*)d_in[1];
    const int*   batch  = (const int*)d_in[2];
    const float* lin0_w = (const float*)d_in[4];
    const float* lin0_b = (const float*)d_in[5];
    const float* r0_wih = (const float*)d_in[6];
    const float* r0_bih = (const float*)d_in[8];
    const float* r0_bhh = (const float*)d_in[9];
    const float* mh1_w  = (const float*)d_in[46];
    const float* mh1_b  = (const float*)d_in[47];
    const float* ln1_g  = (const float*)d_in[48];
    const float* ln1_b  = (const float*)d_in[49];
    const float* mh2_w  = (const float*)d_in[50];
    const float* mh2_b  = (const float*)d_in[51];
    const float* ln2_g  = (const float*)d_in[52];
    const float* ln2_b  = (const float*)d_in[53];
    float* out = (float*)d_out;

    // ---- workspace bump allocation ----
    char* wsb = (char*)d_ws;
    auto alloc = [&](size_t bytes) -> void* {
        void* p = (void*)wsb;
        wsb += (bytes + 255) & ~(size_t)255;
        return p;
    };
    const size_t NH = (size_t)MP * HID;
    float* cb   = (float*)alloc(NH * 4);
    float* yb   = (float*)alloc(NH * 4);
    short* xb   = (short*)yb;                 // alias: xb (MP*320*2=64MB) < yb (102.5MB);
                                              // xb dead before first zero(yb)
    short* hbb  = (short*)alloc(NH * 2);
    short* ybb  = (short*)alloc(NH * 2);
    short* xlb  = (short*)alloc(NH * 2);
    short* xrb  = (short*)alloc(NH * 2);
    float* elog = (float*)alloc((size_t)EP * HEADS * 4);
    float* nmax = (float*)alloc((size_t)NN * HEADS * 4);
    float* nsum = (float*)alloc((size_t)NN * HEADS * 4);
    float* gbuf = (float*)xrb;                // alias: CHKP*1024*4=26.2MB < xr; xr dead in LSTM phase
    // weight pack (bf16)
    short* w_lin0 = (short*)alloc((size_t)256 * KP0 * 2);
    short* w_r0   = (short*)alloc((size_t)1024 * 256 * 2);
    short* w_wl[3]; short* w_wr[3]; short* w_ih[3]; short* w_hh[3];
    for (int l = 0; l < 3; ++l) {
        int Kp = (l == 0) ? KP0 : 256;
        w_wl[l] = (short*)alloc((size_t)256 * Kp * 2);
        w_wr[l] = (short*)alloc((size_t)256 * Kp * 2);
        w_ih[l] = (short*)alloc((size_t)1024 * 256 * 2);
        w_hh[l] = (short*)alloc((size_t)1024 * 256 * 2);
    }
    short* w_m1 = (short*)alloc((size_t)NH1 * 256 * 2);
    short* w_m2 = (short*)alloc((size_t)NH2 * NH1 * 2);
    // tail aliases over xlb (dead after last edge_scatter)
    float* pooled = (float*)xlb;
    float* cnt    = pooled + (size_t)BG * HID;
    float* z1     = cnt + BG;
    short* z1b    = (short*)(z1 + (size_t)BG * NH1);
    short* poolb  = z1b + (size_t)BG * NH1;

    auto zero = [&](float* p, long long n) {
        zero_f32<<<dim3(2048), dim3(256), 0, stream>>>(p, n);
    };
    auto conv = [&](const float* s, short* d, int rs, int rd, int Ks, int Kd) {
        conv_bf16<<<dim3(512), dim3(256), 0, stream>>>(s, d, rs, rd, Ks, Kd);
    };
    auto G = [&](const short* A1, const short* B1, int K1,
                 const short* A2, const short* B2, int K2,
                 const float* b1, const float* b2,
                 float* Cf, short* Cbb, int M, int N) {
        mfma_gemm<<<dim3(M / 128, N / 128), dim3(256), 0, stream>>>(
            A1, B1, K1, A2, B2, K2, b1, b2, Cf, Cbb, N);
    };

    // ---- weight + input conversions ----
    conv(x, xb, NN, MP, FIN, KP0);
    conv(lin0_w, w_lin0, 256, 256, FIN, KP0);
    conv(r0_wih, w_r0, 1024, 1024, 256, 256);
    for (int l = 0; l < 3; ++l) {
        int base = 10 + 12 * l;
        int K  = (l == 0) ? FIN : 256;
        int Kp = (l == 0) ? KP0 : 256;
        conv((const float*)d_in[base + 0], w_wl[l], 256, 256, K, Kp);
        conv((const float*)d_in[base + 2], w_wr[l], 256, 256, K, Kp);
        conv((const float*)d_in[base + 8], w_ih[l], 1024, 1024, 256, 256);
        conv((const float*)d_in[base + 9], w_hh[l], 1024, 1024, 256, 256);
    }
    conv(mh1_w, w_m1, NH1, NH1, 256, 256);
    conv(mh2_w, w_m2, NH2, NH2, NH1, NH1);
    zero(cb, (long long)NH);

    // ---- lin0 -> ybb (bf16, bias fused); rnn0 LSTM from zero state ----
    G(xb, w_lin0, KP0, nullptr, nullptr, 0, lin0_b, nullptr, nullptr, ybb, MP, HID);
    for (int r0 = 0; r0 < MP; r0 += CHKP) {
        int rows = min(CHKP, MP - r0);
        G(ybb + (size_t)r0 * HID, w_r0, 256, nullptr, nullptr, 0,
          r0_bih, r0_bhh, gbuf, nullptr, rows, G4H);
        lstm_update<<<dim3(rows), dim3(256), 0, stream>>>(gbuf, hbb, cb, rows, r0);
    }

    // ---- 3x (GATv2 -> LN+ELU -> LSTM) ----
    for (int l = 0; l < 3; ++l) {
        int base = 10 + 12 * l;
        const float* bl  = (const float*)d_in[base + 1];
        const float* br  = (const float*)d_in[base + 3];
        const float* att = (const float*)d_in[base + 4];
        const float* gb  = (const float*)d_in[base + 5];
        const float* lg  = (const float*)d_in[base + 6];
        const float* lb  = (const float*)d_in[base + 7];
        const float* bih = (const float*)d_in[base + 10];
        const float* bhh = (const float*)d_in[base + 11];
        const short* Ain = (l == 0) ? xb : hbb;
        int K = (l == 0) ? KP0 : 256;

        G(Ain, w_wl[l], K, nullptr, nullptr, 0, bl, nullptr, nullptr, xlb, MP, HID);
        G(Ain, w_wr[l], K, nullptr, nullptr, 0, br, nullptr, nullptr, xrb, MP, HID);
        init_gat<<<dim3((NN * HEADS + 255) / 256), dim3(256), 0, stream>>>(nmax, nsum);
        zero(yb, (long long)NN * HID);   // also kills xb alias (safe: after last xb read)
        edge_logits<<<dim3((EP + 3) / 4), dim3(256), 0, stream>>>(xlb, xrb, ei, att, elog, nmax);
        edge_alpha<<<dim3((EP * HEADS + 255) / 256), dim3(256), 0, stream>>>(elog, nmax, nsum, ei);
        edge_scatter<<<dim3((EP + 3) / 4), dim3(256), 0, stream>>>(elog, nsum, xlb, ei, yb);
        ln_act_kernel<<<dim3(NN), dim3(256), 0, stream>>>(yb, gb, lg, lb, nullptr, ybb, HID, 2);
        // fused dual-source gates: ybb@wih^T + hbb@whh^T (gbuf aliases xrb)
        for (int r0 = 0; r0 < MP; r0 += CHKP) {
            int rows = min(CHKP, MP - r0);
            G(ybb + (size_t)r0 * HID, w_ih[l], 256,
              hbb + (size_t)r0 * HID, w_hh[l], 256,
              bih, bhh, gbuf, nullptr, rows, G4H);
            lstm_update<<<dim3(rows), dim3(256), 0, stream>>>(gbuf, hbb, cb, rows, r0);
        }
    }

    // ---- mean pool + MLP head ----
    zero(pooled, (long long)BG * HID + BG);
    pool_sum<<<dim3((NN + 3) / 4), dim3(256), 0, stream>>>(hbb, batch, pooled, cnt);
    pool_div<<<dim3((BG * HID + 255) / 256), dim3(256), 0, stream>>>(pooled, cnt, poolb);

    G(poolb, w_m1, 256, nullptr, nullptr, 0, mh1_b, nullptr, z1, nullptr, BG, NH1);
    ln_act_kernel<<<dim3(BG), dim3(256), 0, stream>>>(z1, nullptr, ln1_g, ln1_b, nullptr, z1b, NH1, 1);
    G(z1b, w_m2, NH1, nullptr, nullptr, 0, mh2_b, nullptr, out, nullptr, BG, NH2);
    ln_act_kernel<<<dim3(BG), dim3(256), 0, stream>>>(out, nullptr, ln2_g, ln2_b, out, nullptr, NH2, 0);
}

// Round 6
// 2573.775 us; speedup vs baseline: 5.4429x; 1.7759x over previous
//
#include <hip/hip_runtime.h>
#include <hip/hip_bf16.h>
#include <math.h>

// ---------------------------------------------------------------------------
// GraphEncoder round 6 (= round-5 resubmission; that bench died on container
// infra before launch):
//  - CSR (built per launch) + fully fused GAT kernel (online softmax +
//    bias + LayerNorm + ELU in one wave per dst node). No atomics, no elog.
//  - LSTM pointwise fused into GEMM epilogue via gate-interleaved weight
//    packing (col p <-> (channel, gate)); gates never touch memory.
//  - Sorted-batch mean pool via binary search (no atomics).
// Workspace (~431 MB): cb f32 | hA,hB,ybb bf16 | xlr bf16 | CSR | weights |
//   xb bf16 (layer-0 input, K-padded) with head temps aliased over it.
// ---------------------------------------------------------------------------

constexpr int NN    = 100000;
constexpr int EE    = 400000;
constexpr int EP    = EE + NN;      // 500000 (incl self loops)
constexpr int BG    = 4096;
constexpr int FIN   = 300;
constexpr int HEADS = 4;
constexpr int HID   = 256;
constexpr int G4H   = 1024;
constexpr int NH1   = 512;
constexpr int NH2   = 768;
constexpr int MP    = 100096;       // 782*128
constexpr int KP0   = 320;          // FIN padded to mult of 32

typedef __attribute__((ext_vector_type(4))) float f32x4;
typedef __attribute__((ext_vector_type(8))) short s16x8;

__device__ inline float sigm(float x) { return 1.f / (1.f + expf(-x)); }
__device__ inline float b2f(short s) { return __uint_as_float(((unsigned)(unsigned short)s) << 16); }
__device__ inline short f2b(float f) {
    unsigned u = __float_as_uint(f);
    u += 0x7fff + ((u >> 16) & 1);          // round-to-nearest-even
    return (short)(u >> 16);
}
__device__ inline float wsum64(float v) {
#pragma unroll
    for (int o = 32; o > 0; o >>= 1) v += __shfl_xor(v, o);
    return v;
}

// ---------------- utility kernels -------------------------------------------
__global__ __launch_bounds__(256) void zero_f32(float* __restrict__ p, long long n)
{
    long long i = (long long)blockIdx.x * 256 + threadIdx.x;
    long long stride = (long long)gridDim.x * 256;
    for (; i < n; i += stride) p[i] = 0.f;
}

// f32 -> bf16 with row/col zero padding
__global__ __launch_bounds__(256) void conv_bf16(
    const float* __restrict__ src, short* __restrict__ dst,
    int rsrc, int rdst, int Ks, int Kd)
{
    long long n = (long long)rdst * Kd;
    long long stride = (long long)gridDim.x * 256;
    for (long long i = (long long)blockIdx.x * 256 + threadIdx.x; i < n; i += stride) {
        int r = (int)(i / Kd);
        int k = (int)(i - (long long)r * Kd);
        float v = (r < rsrc && k < Ks) ? src[(long long)r * Ks + k] : 0.f;
        dst[i] = f2b(v);
    }
}

// gate-interleaved pack of LSTM weight [1024][K]:
// new row p -> orig row gate*256+ch, gate=(p>>4)&3, ch=(p>>7)*32+((p>>6)&1)*16+(p&15)
__global__ __launch_bounds__(256) void conv_gates(
    const float* __restrict__ src, short* __restrict__ dst, int K)
{
    long long n = (long long)G4H * K;
    long long stride = (long long)gridDim.x * 256;
    for (long long i = (long long)blockIdx.x * 256 + threadIdx.x; i < n; i += stride) {
        int p = (int)(i / K);
        int k = (int)(i - (long long)p * K);
        int gate = (p >> 4) & 3;
        int ch   = (p >> 7) * 32 + ((p >> 6) & 1) * 16 + (p & 15);
        dst[i] = f2b(src[(size_t)(gate * 256 + ch) * K + k]);
    }
}

__global__ __launch_bounds__(256) void concat2_f32(
    const float* __restrict__ a, const float* __restrict__ b,
    float* __restrict__ dst, int na, int nb)
{
    int i = blockIdx.x * 256 + threadIdx.x;
    if (i < na) dst[i] = a[i];
    else if (i < na + nb) dst[i] = b[i - na];
}

// ---------------- CSR build -------------------------------------------------
__global__ __launch_bounds__(256) void edge_hist(const int* __restrict__ ei,
                                                 int* __restrict__ deg)
{
    int e = blockIdx.x * 256 + threadIdx.x;
    if (e >= EP) return;
    int d = (e < EE) ? ei[EE + e] : e - EE;
    atomicAdd(&deg[d], 1);
}

__global__ __launch_bounds__(1024) void scan_deg(const int* __restrict__ deg,
                                                 int* __restrict__ rowptr,
                                                 int* __restrict__ cursor)
{
    __shared__ int part[1024];
    int t = threadIdx.x;
    const int CH = (NN + 1023) / 1024;
    int lo = t * CH, hi = min(lo + CH, NN);
    int s = 0;
    for (int i = lo; i < hi; ++i) s += deg[i];
    part[t] = s;
    __syncthreads();
    for (int off = 1; off < 1024; off <<= 1) {
        int v = (t >= off) ? part[t - off] : 0;
        __syncthreads();
        part[t] += v;
        __syncthreads();
    }
    int run = (t == 0) ? 0 : part[t - 1];
    for (int i = lo; i < hi; ++i) { rowptr[i] = run; cursor[i] = 0; run += deg[i]; }
    if (t == 1023) rowptr[NN] = run;   // == EP
}

__global__ __launch_bounds__(256) void edge_fill(const int* __restrict__ ei,
                                                 const int* __restrict__ rowptr,
                                                 int* __restrict__ cursor,
                                                 int* __restrict__ esrc)
{
    int e = blockIdx.x * 256 + threadIdx.x;
    if (e >= EP) return;
    int s, d;
    if (e < EE) { s = ei[e]; d = ei[EE + e]; }
    else        { s = d = e - EE; }
    int slot = rowptr[d] + atomicAdd(&cursor[d], 1);
    esrc[slot] = s;
}

// ---------------- MFMA GEMM with fused epilogues ----------------------------
// C[M x N] = A1[M x K1] @ B1[N x K1]^T (+ A2[M x K2] @ B2[N x K2]^T)
// mode 0: +bias -> f32 Cf      mode 1: +bias -> bf16 Cb
// mode 2: LSTM epilogue (gate-interleaved B; N=1024): reads c_in (or 0),
//         writes c_out f32 + h_out bf16, both [M][256].
__global__ __launch_bounds__(256) void mfma_gemm(
    const short* __restrict__ A1, const short* __restrict__ B1, int K1,
    const short* __restrict__ A2, const short* __restrict__ B2, int K2,
    const float* __restrict__ bias,
    const float* __restrict__ bih, const float* __restrict__ bhh,
    const float* __restrict__ c_in, float* __restrict__ c_out,
    short* __restrict__ h_out,
    float* __restrict__ Cf, short* __restrict__ Cb, int N, int mode)
{
    __shared__ __align__(16) short sA[128 * 32];
    __shared__ __align__(16) short sB[128 * 32];
    const int tid  = threadIdx.x;
    const int w    = tid >> 6, lane = tid & 63;
    const int wr   = w >> 1,  wc   = w & 1;      // 2x2 waves of 64x64
    const int row0 = blockIdx.x * 128, col0 = blockIdx.y * 128;

    f32x4 acc[4][4];
#pragma unroll
    for (int m = 0; m < 4; ++m)
#pragma unroll
        for (int n = 0; n < 4; ++n) acc[m][n] = (f32x4){0.f, 0.f, 0.f, 0.f};

    const int rs = lane >> 2;
    const int cs = lane & 3;
    const int KK = K1 + K2;

    for (int k0 = 0; k0 < KK; k0 += 32) {
        const short* Ak; const short* Bk; int kk, ld;
        if (k0 < K1) { Ak = A1; Bk = B1; kk = k0;      ld = K1; }
        else         { Ak = A2; Bk = B2; kk = k0 - K1; ld = K2; }
#pragma unroll
        for (int i = 0; i < 2; ++i) {
            int seg = w * 2 + i;
            int row = seg * 16 + rs;
            int c8  = cs ^ ((row + (row >> 2)) & 3);
            const short* ga = Ak + (size_t)(row0 + row) * ld + kk + c8 * 8;
            const short* gb = Bk + (size_t)(col0 + row) * ld + kk + c8 * 8;
            short* la = sA + seg * 512 + lane * 8;
            short* lb = sB + seg * 512 + lane * 8;
            __builtin_amdgcn_global_load_lds((const __attribute__((address_space(1))) void*)ga,
                                             (__attribute__((address_space(3))) void*)la, 16, 0, 0);
            __builtin_amdgcn_global_load_lds((const __attribute__((address_space(1))) void*)gb,
                                             (__attribute__((address_space(3))) void*)lb, 16, 0, 0);
        }
        __syncthreads();

        s16x8 af[4], bg[4];
        {
            const int rl = lane & 15;
            const int cw = lane >> 4;
#pragma unroll
            for (int m = 0; m < 4; ++m) {
                int r  = wr * 64 + m * 16 + rl;
                int sl = cw ^ ((r + (r >> 2)) & 3);
                af[m] = *(const s16x8*)(sA + r * 32 + sl * 8);
                int c  = wc * 64 + m * 16 + rl;
                int sc = cw ^ ((c + (c >> 2)) & 3);
                bg[m] = *(const s16x8*)(sB + c * 32 + sc * 8);
            }
        }
#pragma unroll
        for (int m = 0; m < 4; ++m)
#pragma unroll
            for (int n = 0; n < 4; ++n)
                acc[m][n] = __builtin_amdgcn_mfma_f32_16x16x32_bf16(af[m], bg[n], acc[m][n], 0, 0, 0);
        __syncthreads();
    }

    // C/D layout: col=lane&15, row=(lane>>4)*4+reg
    const int l16   = lane & 15;
    const int rbase = row0 + wr * 64 + (lane >> 4) * 4;
    if (mode == 2) {
        const int ch = blockIdx.y * 32 + wc * 16 + l16;
        float bi[4];
#pragma unroll
        for (int g = 0; g < 4; ++g) bi[g] = bih[g * 256 + ch] + bhh[g * 256 + ch];
#pragma unroll
        for (int m = 0; m < 4; ++m) {
#pragma unroll
            for (int r = 0; r < 4; ++r) {
                int row = rbase + m * 16 + r;
                float gi = acc[m][0][r] + bi[0];
                float gf = acc[m][1][r] + bi[1];
                float gg = acc[m][2][r] + bi[2];
                float go = acc[m][3][r] + bi[3];
                size_t idx = (size_t)row * HID + ch;
                float co = c_in ? c_in[idx] : 0.f;
                float c2 = sigm(gf) * co + sigm(gi) * tanhf(gg);
                float h2 = sigm(go) * tanhf(c2);
                c_out[idx] = c2;
                h_out[idx] = f2b(h2);
            }
        }
    } else {
        const int cbase = col0 + wc * 64 + l16;
#pragma unroll
        for (int n = 0; n < 4; ++n) {
            int col = cbase + n * 16;
            float ba = bias ? bias[col] : 0.f;
#pragma unroll
            for (int m = 0; m < 4; ++m) {
#pragma unroll
                for (int r = 0; r < 4; ++r) {
                    int row = rbase + m * 16 + r;
                    float v = acc[m][n][r] + ba;
                    size_t idx = (size_t)row * N + col;
                    if (mode == 1) Cb[idx] = f2b(v);
                    else           Cf[idx] = v;
                }
            }
        }
    }
}

// ---------------- fused GATv2 (softmax + aggregate + bias + LN + ELU) -------
// one 64-lane wave per dst node; lane l = channel h*64+l per head h.
// xlr: [MP][512] bf16, cols 0..255 = lin_l(x), 256..511 = lin_r(x).
__global__ __launch_bounds__(256) void gat_fused(
    const short* __restrict__ xlr, const int* __restrict__ rowptr,
    const int* __restrict__ esrc, const float* __restrict__ att,
    const float* __restrict__ gb, const float* __restrict__ lg,
    const float* __restrict__ lb, short* __restrict__ outb)
{
    int i    = blockIdx.x * 4 + (threadIdx.x >> 6);
    int lane = threadIdx.x & 63;
    if (i >= NN) return;
    float xr[HEADS], at[HEADS];
#pragma unroll
    for (int h = 0; h < HEADS; ++h) {
        xr[h] = b2f(xlr[(size_t)i * 512 + 256 + h * 64 + lane]);
        at[h] = att[h * 64 + lane];
    }
    float mx[HEADS], sm[HEADS], ac[HEADS];
#pragma unroll
    for (int h = 0; h < HEADS; ++h) { mx[h] = -INFINITY; sm[h] = 0.f; ac[h] = 0.f; }

    int lo = rowptr[i], hi = rowptr[i + 1];
    for (int e = lo; e < hi; ++e) {
        int s = esrc[e];
        float xs[HEADS], p[HEADS];
#pragma unroll
        for (int h = 0; h < HEADS; ++h) {
            xs[h] = b2f(xlr[(size_t)s * 512 + h * 64 + lane]);
            float v = xs[h] + xr[h];
            v = (v >= 0.f) ? v : 0.2f * v;
            p[h] = v * at[h];
        }
#pragma unroll
        for (int h = 0; h < HEADS; ++h) p[h] = wsum64(p[h]);
#pragma unroll
        for (int h = 0; h < HEADS; ++h) {
            float mn = fmaxf(mx[h], p[h]);
            float sc = expf(mx[h] - mn);     // first iter: exp(-inf)=0
            float a  = expf(p[h] - mn);
            sm[h] = sm[h] * sc + a;
            ac[h] = ac[h] * sc + a * xs[h];
            mx[h] = mn;
        }
    }
    // y = ac/sm (+ gat bias), then LayerNorm(256) + ELU, write bf16
    float val[HEADS], s1 = 0.f, s2 = 0.f;
#pragma unroll
    for (int h = 0; h < HEADS; ++h) {
        float v = ac[h] / sm[h] + gb[h * 64 + lane];
        val[h] = v; s1 += v; s2 += v * v;
    }
    s1 = wsum64(s1); s2 = wsum64(s2);
    float mean = s1 * (1.f / 256.f);
    float var  = s2 * (1.f / 256.f) - mean * mean;
    float inv  = rsqrtf(var + 1e-5f);
#pragma unroll
    for (int h = 0; h < HEADS; ++h) {
        float v = (val[h] - mean) * inv * lg[h * 64 + lane] + lb[h * 64 + lane];
        v = (v > 0.f) ? v : expm1f(v);
        outb[(size_t)i * HID + h * 64 + lane] = f2b(v);
    }
}

// ---------------- LayerNorm (+act) for the MLP head -------------------------
__global__ __launch_bounds__(256) void ln_act_kernel(
    const float* __restrict__ in, const float* __restrict__ gamma,
    const float* __restrict__ beta, float* __restrict__ outf,
    short* __restrict__ outb, int width, int act)
{
    int row = blockIdx.x;
    const float* ip = in + (size_t)row * width;
    float vals[3];
    float s = 0.f, ss = 0.f;
    int nw = width >> 8;
    for (int i = 0; i < nw; ++i) {
        int c = threadIdx.x + (i << 8);
        float v = ip[c];
        vals[i] = v; s += v; ss += v * v;
    }
#pragma unroll
    for (int off = 32; off > 0; off >>= 1) {
        s  += __shfl_down(s, off);
        ss += __shfl_down(ss, off);
    }
    __shared__ float sh[8];
    int wv = threadIdx.x >> 6, lane = threadIdx.x & 63;
    if (lane == 0) { sh[wv] = s; sh[4 + wv] = ss; }
    __syncthreads();
    if (threadIdx.x == 0) {
        sh[0] = sh[0] + sh[1] + sh[2] + sh[3];
        sh[4] = sh[4] + sh[5] + sh[6] + sh[7];
    }
    __syncthreads();
    float mean = sh[0] / width;
    float var  = sh[4] / width - mean * mean;
    float inv  = rsqrtf(var + 1e-5f);
    for (int i = 0; i < nw; ++i) {
        int c = threadIdx.x + (i << 8);
        float v = (vals[i] - mean) * inv * gamma[c] + beta[c];
        if (act == 1) v = fmaxf(v, 0.f);
        if (outb) outb[(size_t)row * width + c] = f2b(v);
        else      outf[(size_t)row * width + c] = v;
    }
}

// ---------------- sorted-batch mean pool ------------------------------------
__global__ __launch_bounds__(256) void pool_mean(
    const short* __restrict__ h, const int* __restrict__ batch,
    short* __restrict__ poolb)
{
    int b    = blockIdx.x * 4 + (threadIdx.x >> 6);
    int lane = threadIdx.x & 63;
    if (b >= BG) return;
    auto lbound = [&](int key) {
        int lo = 0, hi = NN;
        while (lo < hi) { int mid = (lo + hi) >> 1; if (batch[mid] < key) lo = mid + 1; else hi = mid; }
        return lo;
    };
    int lo = lbound(b), hi = lbound(b + 1);
    float acc[HEADS] = {0.f, 0.f, 0.f, 0.f};
    for (int r = lo; r < hi; ++r)
#pragma unroll
        for (int hh = 0; hh < HEADS; ++hh)
            acc[hh] += b2f(h[(size_t)r * HID + hh * 64 + lane]);
    float inv = 1.f / fmaxf((float)(hi - lo), 1.f);
#pragma unroll
    for (int hh = 0; hh < HEADS; ++hh)
        poolb[(size_t)b * HID + hh * 64 + lane] = f2b(acc[hh] * inv);
}

// ---------------------------------------------------------------------------
extern "C" void kernel_launch(void* const* d_in, const int* in_sizes, int n_in,
                              void* d_out, int out_size, void* d_ws, size_t ws_size,
                              hipStream_t stream)
{
    (void)in_sizes; (void)n_in; (void)out_size; (void)ws_size;
    const float* x      = (const float*)d_in[0];
    const int*   ei     = (const int*)d_in[1];
    const int*   batch  = (const int*)d_in[2];
    const float* lin0_w = (const float*)d_in[4];
    const float* lin0_b = (const float*)d_in[5];
    const float* r0_wih = (const float*)d_in[6];
    const float* r0_bih = (const float*)d_in[8];
    const float* r0_bhh = (const float*)d_in[9];
    const float* mh1_w  = (const float*)d_in[46];
    const float* mh1_b  = (const float*)d_in[47];
    const float* ln1_g  = (const float*)d_in[48];
    const float* ln1_b  = (const float*)d_in[49];
    const float* mh2_w  = (const float*)d_in[50];
    const float* mh2_b  = (const float*)d_in[51];
    const float* ln2_g  = (const float*)d_in[52];
    const float* ln2_b  = (const float*)d_in[53];
    float* out = (float*)d_out;

    // ---- workspace bump allocation ----
    char* wsb = (char*)d_ws;
    auto alloc = [&](size_t bytes) -> void* {
        void* p = (void*)wsb;
        wsb += (bytes + 255) & ~(size_t)255;
        return p;
    };
    const size_t NH = (size_t)MP * HID;
    float* cb   = (float*)alloc(NH * 4);          // LSTM cell state f32
    short* hA   = (short*)alloc(NH * 2);          // h ping
    short* hB   = (short*)alloc(NH * 2);          // h pong
    short* ybb  = (short*)alloc(NH * 2);          // LSTM-input / x0 bf16
    short* xlr  = (short*)alloc((size_t)MP * 512 * 2);  // [xl|xr] bf16
    int*   deg    = (int*)alloc((size_t)NN * 4);
    int*   rowptr = (int*)alloc((size_t)(NN + 1) * 4);
    int*   cursor = (int*)alloc((size_t)NN * 4);
    int*   esrc   = (int*)alloc((size_t)EP * 4);
    // weights bf16
    short* w_lin0 = (short*)alloc((size_t)256 * KP0 * 2);
    short* w_r0   = (short*)alloc((size_t)G4H * 256 * 2);
    short* w_lr[3]; short* w_ih[3]; short* w_hh[3]; float* blr[3];
    for (int l = 0; l < 3; ++l) {
        int Kp = (l == 0) ? KP0 : 256;
        w_lr[l] = (short*)alloc((size_t)512 * Kp * 2);
        w_ih[l] = (short*)alloc((size_t)G4H * 256 * 2);
        w_hh[l] = (short*)alloc((size_t)G4H * 256 * 2);
        blr[l]  = (float*)alloc(512 * 4);
    }
    short* w_m1 = (short*)alloc((size_t)NH1 * 256 * 2);
    short* w_m2 = (short*)alloc((size_t)NH2 * NH1 * 2);
    // xb (layer-0 padded input) with head temps aliased over it (head runs
    // only after xb is dead)
    short* xb = (short*)alloc((size_t)MP * KP0 * 2);   // 64 MB
    float* z1    = (float*)xb;                          // BG*NH1 f32 (8.4MB)
    short* z1b   = (short*)(z1 + (size_t)BG * NH1);     // BG*NH1 bf16
    short* poolb = z1b + (size_t)BG * NH1;              // BG*HID bf16

    auto conv = [&](const float* s, short* d, int rs, int rd, int Ks, int Kd) {
        conv_bf16<<<dim3(512), dim3(256), 0, stream>>>(s, d, rs, rd, Ks, Kd);
    };
    auto convg = [&](const float* s, short* d) {
        conv_gates<<<dim3(512), dim3(256), 0, stream>>>(s, d, 256);
    };
    // mode 0/1 GEMM
    auto G = [&](const short* A, const short* B, int K, const float* bias,
                 float* Cf, short* Cbb, int M, int N, int mode) {
        mfma_gemm<<<dim3(M / 128, N / 128), dim3(256), 0, stream>>>(
            A, B, K, nullptr, nullptr, 0, bias,
            nullptr, nullptr, nullptr, nullptr, nullptr, Cf, Cbb, N, mode);
    };
    // mode 2 LSTM GEMM
    auto GL = [&](const short* A1, const short* B1, int K1,
                  const short* A2, const short* B2, int K2,
                  const float* bih, const float* bhh,
                  const float* ci, float* co, short* ho) {
        mfma_gemm<<<dim3(MP / 128, G4H / 128), dim3(256), 0, stream>>>(
            A1, B1, K1, A2, B2, K2, nullptr,
            bih, bhh, ci, co, ho, nullptr, nullptr, G4H, 2);
    };

    // ---- conversions + CSR build ----
    conv(x, xb, NN, MP, FIN, KP0);
    conv(lin0_w, w_lin0, 256, 256, FIN, KP0);
    convg(r0_wih, w_r0);
    for (int l = 0; l < 3; ++l) {
        int base = 10 + 12 * l;
        int K  = (l == 0) ? FIN : 256;
        int Kp = (l == 0) ? KP0 : 256;
        conv((const float*)d_in[base + 0], w_lr[l], 256, 256, K, Kp);
        conv((const float*)d_in[base + 2], w_lr[l] + (size_t)256 * Kp, 256, 256, K, Kp);
        convg((const float*)d_in[base + 8], w_ih[l]);
        convg((const float*)d_in[base + 9], w_hh[l]);
        concat2_f32<<<dim3(2), dim3(256), 0, stream>>>(
            (const float*)d_in[base + 1], (const float*)d_in[base + 3], blr[l], 256, 256);
    }
    conv(mh1_w, w_m1, NH1, NH1, 256, 256);
    conv(mh2_w, w_m2, NH2, NH2, NH1, NH1);

    zero_f32<<<dim3(256), dim3(256), 0, stream>>>((float*)deg, NN);
    edge_hist<<<dim3((EP + 255) / 256), dim3(256), 0, stream>>>(ei, deg);
    scan_deg<<<dim3(1), dim3(1024), 0, stream>>>(deg, rowptr, cursor);
    edge_fill<<<dim3((EP + 255) / 256), dim3(256), 0, stream>>>(ei, rowptr, cursor, esrc);

    // ---- lin0 -> x0 (bf16); rnn0 LSTM from zero state (fused epilogue) ----
    G(xb, w_lin0, KP0, lin0_b, nullptr, ybb, MP, HID, 1);
    GL(ybb, w_r0, 256, nullptr, nullptr, 0, r0_bih, r0_bhh, nullptr, cb, hA);

    // ---- 3x (GATv2 -> LN+ELU -> LSTM) ----
    short* hprev = hA;
    short* hnext = hB;
    for (int l = 0; l < 3; ++l) {
        int base = 10 + 12 * l;
        const float* att = (const float*)d_in[base + 4];
        const float* gb  = (const float*)d_in[base + 5];
        const float* lg  = (const float*)d_in[base + 6];
        const float* lb  = (const float*)d_in[base + 7];
        const float* bih = (const float*)d_in[base + 10];
        const float* bhh = (const float*)d_in[base + 11];
        const short* Ain = (l == 0) ? xb : hprev;
        int K = (l == 0) ? KP0 : 256;

        G(Ain, w_lr[l], K, blr[l], nullptr, xlr, MP, 512, 1);
        gat_fused<<<dim3((NN + 3) / 4), dim3(256), 0, stream>>>(
            xlr, rowptr, esrc, att, gb, lg, lb, ybb);
        GL(ybb, w_ih[l], 256, hprev, w_hh[l], 256, bih, bhh, cb, cb, hnext);
        short* t = hprev; hprev = hnext; hnext = t;
    }

    // ---- mean pool (sorted batch) + MLP head ----
    pool_mean<<<dim3((BG + 3) / 4), dim3(256), 0, stream>>>(hprev, batch, poolb);
    G(poolb, w_m1, 256, mh1_b, z1, nullptr, BG, NH1, 0);
    ln_act_kernel<<<dim3(BG), dim3(256), 0, stream>>>(z1, ln1_g, ln1_b, nullptr, z1b, NH1, 1);
    G(z1b, w_m2, NH1, mh2_b, out, nullptr, BG, NH2, 0);
    ln_act_kernel<<<dim3(BG), dim3(256), 0, stream>>>(out, ln2_g, ln2_b, out, nullptr, NH2, 0);
}